// Round 10
// baseline (162.563 us; speedup 1.0000x reference)
//
#include <hip/hip_runtime.h>

// Head: B=4 T=4096 E=768 H=64, causal attention, single head.
// Round 16: attn LDS halved (37.9KB -> 18.9KB) to test the 1-block/CU model.
// Model (fits R6/R9/R10 quantitatively): at 37.9KB only 1 block/CU schedules
// (64KB pool) -> 512 blocks = TWO sequential rounds; R6's descending order
// is LPT backfill (44us), R9's ascending round-2 was worst-case LPT (53us).
// Fix: stage P one mt-tile at a time (store0->PV0->store1->QK(u+8)->PV1;
// sacc consumed before QK overwrites). sbuf 8x1152, lpart 8x16 -> 18944B ->
// 2 blocks/CU -> heavy+light concurrent, no round 2. Epilogue per-mt.
//  qkv/wt: HELD at R14 (pipelined staging). attn mapping/bounds unchanged.
// Ledger: (512,2) bound mandatory (cap=256/arg2, arg2>2 spills). Heavy-first
// z->qt. lsum via ones-MFMA (R15). Trunc P-store (R13).
// Softmax without max-subtraction (logits bounded), Q pre-scaled 0.125*log2e.

#define BB 4
#define TT 4096
#define EE 768
#define HH 64
#define BT (BB*TT)

typedef __attribute__((ext_vector_type(8))) short short8;
typedef __attribute__((ext_vector_type(4))) float f32x4;
#define MFMA16(a,b,c) __builtin_amdgcn_mfma_f32_16x16x32_bf16(a,b,c,0,0,0)
#define QSCALE 0.18033688011112042f   // 0.125 * log2(e)

static __device__ __forceinline__ float bflo(unsigned a){ return __uint_as_float(a << 16); }
static __device__ __forceinline__ unsigned short f2bf(float f){
    unsigned x = __float_as_uint(f);
    x += 0x7fffu + ((x >> 16) & 1u);   // RNE
    return (unsigned short)(x >> 16);
}
template<int FP32>
static __device__ __forceinline__ float ldin(const void* p, int idx){
    if (FP32) return ((const float*)p)[idx];
    return bflo(((const unsigned short*)p)[idx]);
}

// ---------------- W transpose + fused dtype probe ----------------
template<int FP32>
static __device__ void wt_body(const void* W, int wi, int e0, unsigned short* wt){
    __shared__ unsigned short ts[64 * 72];
    const int tid = threadIdx.x;
    #pragma unroll
    for (int p = 0; p < 2; p++){
        int i = p * 256 + tid;
        int r = i >> 3, g = i & 7;
        unsigned short v[8];
        if (FP32){
            const float* src = (const float*)W + (size_t)(e0 + r) * HH + g * 8;
            const float4 a = *(const float4*)src, b = *(const float4*)(src + 4);
            v[0]=f2bf(a.x); v[1]=f2bf(a.y); v[2]=f2bf(a.z); v[3]=f2bf(a.w);
            v[4]=f2bf(b.x); v[5]=f2bf(b.y); v[6]=f2bf(b.z); v[7]=f2bf(b.w);
        } else {
            const unsigned short* src = (const unsigned short*)W + (size_t)(e0 + r) * HH + g * 8;
            #pragma unroll
            for (int j = 0; j < 8; j++) v[j] = src[j];
        }
        #pragma unroll
        for (int j = 0; j < 8; j++) ts[r * 72 + g * 8 + j] = v[j];
    }
    __syncthreads();
    #pragma unroll
    for (int p = 0; p < 2; p++){
        int i = p * 256 + tid;
        int h = i >> 3, g = i & 7;
        unsigned short v[8];
        #pragma unroll
        for (int j = 0; j < 8; j++) v[j] = ts[(g * 8 + j) * 72 + h];
        unsigned short* dst = wt + (size_t)(wi * 64 + h) * EE + e0 + g * 8;
        uint4 pk;
        pk.x = (unsigned)v[0] | ((unsigned)v[1] << 16);
        pk.y = (unsigned)v[2] | ((unsigned)v[3] << 16);
        pk.z = (unsigned)v[4] | ((unsigned)v[5] << 16);
        pk.w = (unsigned)v[6] | ((unsigned)v[7] << 16);
        *(uint4*)dst = pk;
    }
}
__global__ __launch_bounds__(256) void wt_kernel(
    const unsigned short* xu, const void* Wq, const void* Wk, const void* Wv,
    unsigned short* wt, int* flag){
    __shared__ int cnt;
    const int tid = threadIdx.x;
    if (tid == 0) cnt = 0;
    __syncthreads();
    int c = 0;
    #pragma unroll
    for (int i = 0; i < 16; i++){
        unsigned u = xu[tid * 16 + i];
        unsigned e = (u >> 7) & 0xFFu;
        if (e >= 140u) c++;              // |v| >= 2^13 decoded as bf16
    }
    atomicAdd(&cnt, c);
    __syncthreads();
    const int fp32 = (cnt > 32) ? 1 : 0;
    if (blockIdx.x == 0 && tid == 0) *flag = fp32;
    const int wi = blockIdx.x / 12;
    const int e0 = (blockIdx.x % 12) * 64;
    const void* W = (wi == 0) ? Wq : (wi == 1) ? Wk : Wv;
    if (fp32) wt_body<1>(W, wi, e0, wt);
    else      wt_body<0>(W, wi, e0, wt);
}

// ---------------- QKV: LDS-staged MFMA GEMM, pipelined staging (R14) ----------------
// grid 1024 = (512 m-tiles of 32 rows) x (2 n-halves of 96 cols), block 256.
// c+1's x/W global loads issued into regs during c's MFMA window.
template<int FP32>
static __device__ void qkv_body(const void* x, const unsigned short* wt,
    const void* bq, const void* bk, const void* bv,
    unsigned short* Qw, unsigned short* Kw, unsigned short* VTw,
    unsigned short* xs, unsigned short* wsl)
{
    const int tid = threadIdx.x, lane = tid & 63, w = tid >> 6;
    const int l15 = lane & 15, quad = lane >> 4;
    const int z = blockIdx.x;
    const int m0 = (z >> 1) * 32;
    const int nh = z & 1;               // n-half: frags nh*6 .. nh*6+5
    const int rh = (w & 1) * 16;
    const int ngl = (w >> 1) * 3;

    f32x4 acc[3];
    #pragma unroll
    for (int i = 0; i < 3; i++) acc[i] = (f32x4)(0.f);

    const int srow = tid >> 3, sg = tid & 7;

    // per-thread fixed source pointers (c advances by +64 elements)
    const float*          xsF = (const float*)x + (size_t)(m0 + srow) * EE + sg * 8;
    const unsigned short* xsB = (const unsigned short*)x + (size_t)(m0 + srow) * EE + sg * 8;
    const unsigned short* ws0 = wt + (size_t)(nh * 96 + srow) * EE + sg * 8;   // p=0: n=srow
    const unsigned short* ws1 = ws0 + (size_t)32 * EE;                          // p=1: n=32+srow
    const unsigned short* ws2 = ws0 + (size_t)64 * EE;                          // p=2: n=64+srow

    float4 xa, xb;      // FP32 prefetch regs
    short8 xv;          // bf16 prefetch reg
    short8 wr0, wr1, wr2;

    // prologue: issue c=0 loads
    if (FP32){ xa = *(const float4*)xsF; xb = *(const float4*)(xsF + 4); }
    else     { xv = *(const short8*)xsB; }
    wr0 = *(const short8*)ws0;
    wr1 = *(const short8*)ws1;
    wr2 = *(const short8*)ws2;

    for (int c = 0; c < 12; c++){
        __syncthreads();
        // stage x from regs
        {
            short8 v;
            if (FP32){
                v[0]=(short)f2bf(xa.x); v[1]=(short)f2bf(xa.y); v[2]=(short)f2bf(xa.z); v[3]=(short)f2bf(xa.w);
                v[4]=(short)f2bf(xb.x); v[5]=(short)f2bf(xb.y); v[6]=(short)f2bf(xb.z); v[7]=(short)f2bf(xb.w);
            } else {
                v = xv;
            }
            *(short8*)&xs[srow * 72 + sg * 8] = v;
        }
        // stage W from regs (same layout as before: n = p*32+srow, g2 = sg)
        *(short8*)&wsl[(     srow) * 72 + sg * 8] = wr0;
        *(short8*)&wsl[(32 + srow) * 72 + sg * 8] = wr1;
        *(short8*)&wsl[(64 + srow) * 72 + sg * 8] = wr2;
        // issue c+1 loads (WAR-safe: ds_writes above consumed regs at issue);
        // they complete during the MFMA phase below.
        if (c < 11){
            const int c1 = (c + 1) * 64;
            if (FP32){ xa = *(const float4*)(xsF + c1); xb = *(const float4*)(xsF + c1 + 4); }
            else     { xv = *(const short8*)(xsB + c1); }
            wr0 = *(const short8*)(ws0 + c1);
            wr1 = *(const short8*)(ws1 + c1);
            wr2 = *(const short8*)(ws2 + c1);
        }
        __syncthreads();
        #pragma unroll
        for (int kst = 0; kst < 2; kst++){
            const short8 a = *(const short8*)&xs[(rh + l15) * 72 + kst * 32 + quad * 8];
            #pragma unroll
            for (int nf = 0; nf < 3; nf++){
                const short8 bfr = *(const short8*)&wsl[((ngl + nf) * 16 + l15) * 72 + kst * 32 + quad * 8];
                acc[nf] = MFMA16(a, bfr, acc[nf]);
            }
        }
    }
    #pragma unroll
    for (int nf = 0; nf < 3; nf++){
        const int gi = nh * 6 + ngl + nf;   // global frag 0..11
        const int wi = gi >> 2;             // 0=Q 1=K 2=V
        const int h = (gi & 3) * 16 + l15;
        const void* bp = (wi == 0) ? bq : (wi == 1) ? bk : bv;
        const float bias = ldin<FP32>(bp, h);
        if (wi == 0){
            #pragma unroll
            for (int rr = 0; rr < 4; rr++){
                const int tok = m0 + rh + quad * 4 + rr;
                Qw[(size_t)tok * HH + h] = f2bf((acc[nf][rr] + bias) * QSCALE);
            }
        } else if (wi == 1){
            #pragma unroll
            for (int rr = 0; rr < 4; rr++){
                const int tok = m0 + rh + quad * 4 + rr;
                Kw[(size_t)tok * HH + h] = f2bf(acc[nf][rr] + bias);
            }
        } else {
            const int tok0 = m0 + rh + quad * 4;
            const int bloc = tok0 >> 12;
            const int tl = tok0 & 4095;
            uint2 pk;
            pk.x = (unsigned)f2bf(acc[nf][0] + bias) | ((unsigned)f2bf(acc[nf][1] + bias) << 16);
            pk.y = (unsigned)f2bf(acc[nf][2] + bias) | ((unsigned)f2bf(acc[nf][3] + bias) << 16);
            *(uint2*)&VTw[(size_t)(bloc * 64 + h) * TT + tl] = pk;
        }
    }
}
__global__ __launch_bounds__(256, 2) void qkv_kernel(
    const void* x, const unsigned short* wt,
    const void* bq, const void* bk, const void* bv,
    unsigned short* Qw, unsigned short* Kw, unsigned short* VTw, const int* flag){
    __shared__ unsigned short xs[32 * 72];    // 4.6 KB
    __shared__ unsigned short wsl[96 * 72];   // 13.8 KB
    if (*flag) qkv_body<1>(x, wt, bq, bk, bv, Qw, Kw, VTw, xs, wsl);
    else       qkv_body<0>(x, wt, bq, bk, bv, Qw, Kw, VTw, xs, wsl);
}

// ---------------- attn: small-LDS pipelined heavy-first split-K flash ----------------
static __device__ __forceinline__ void qk8(
    const short8 (&qf)[2][2], const short8 (&kf)[4][2], f32x4 (&s)[2][4])
{
    #pragma unroll
    for (int mt = 0; mt < 2; mt++)
        #pragma unroll
        for (int c = 0; c < 4; c++){
            s[mt][c] = (f32x4)(0.f);
            s[mt][c] = MFMA16(qf[mt][0], kf[c][0], s[mt][c]);
            s[mt][c] = MFMA16(qf[mt][1], kf[c][1], s[mt][c]);
        }
}
// grid 512 = (128 qt, heavy first) x (4 b), block 512 = 8 waves = 8 cyclic
// splits. P staged ONE mt-tile at a time -> LDS 18944 B -> 2 blocks/CU.
// __launch_bounds__(512,2): VGPR cap 128 — do not raise arg2.
__global__ __launch_bounds__(512, 2) void attn_kernel(
    const unsigned short* __restrict__ Q,
    const unsigned short* __restrict__ K, const unsigned short* __restrict__ VT,
    void* __restrict__ out, const int* __restrict__ flag)
{
    __shared__ unsigned short sbuf[8][1152];  // per-wave: P[16][72] / Opart[16][72]
    __shared__ float lpart[8][16];

    const int mode = *flag;
    const int z = blockIdx.x;
    const int b = z & 3;
    const int qt = 127 - (z >> 2);        // heavy tiles dispatched first
    const int q0 = qt * 32;
    const int nkb = (qt >> 1) + 1;        // key units; only the last needs masking
    const int tid = threadIdx.x;
    const int lane = tid & 63;
    const int w = tid >> 6;               // wave = split
    const int l15 = lane & 15, quad = lane >> 4;
    const int brow = b * TT;

    const short8 VONES = (short8)(short)0x3F80;  // bf16 1.0 splat (ones B-frag)

    f32x4 O[2][4];
    f32x4 Lk[2];                          // P row-sums via ones-MFMA
    #pragma unroll
    for (int mt = 0; mt < 2; mt++){
        Lk[mt] = (f32x4)(0.f);
        #pragma unroll
        for (int i = 0; i < 4; i++) O[mt][i] = (f32x4)(0.f);
    }

    if (w < nkb){
        // Q A-frags (pre-scaled by QSCALE)
        short8 qf[2][2];
        #pragma unroll
        for (int mt = 0; mt < 2; mt++)
            #pragma unroll
            for (int kst = 0; kst < 2; kst++)
                qf[mt][kst] = *(const short8*)(Q + (size_t)(brow + q0 + mt * 16 + l15) * HH + kst * 32 + quad * 8);

        // K frags for unit w + prologue QK
        short8 kf[4][2];
        #pragma unroll
        for (int c = 0; c < 4; c++)
            #pragma unroll
            for (int kst = 0; kst < 2; kst++)
                kf[c][kst] = *(const short8*)(K + (size_t)(brow + w * 64 + c * 16 + l15) * HH + kst * 32 + quad * 8);

        f32x4 sacc[2][4];
        qk8(qf, kf, sacc);
        if (w + 8 < nkb){
            const int kn0 = (w + 8) * 64;
            #pragma unroll
            for (int c = 0; c < 4; c++)
                #pragma unroll
                for (int kst = 0; kst < 2; kst++)
                    kf[c][kst] = *(const short8*)(K + (size_t)(brow + kn0 + c * 16 + l15) * HH + kst * 32 + quad * 8);
        }

        for (int u = w; u < nkb; u += 8){
            const int k0 = u * 64;
            // V^T frags (issued early, consumed at PV)
            short8 vf[4][2];
            #pragma unroll
            for (int c = 0; c < 4; c++)
                #pragma unroll
                for (int kst = 0; kst < 2; kst++)
                    vf[c][kst] = *(const short8*)(VT + (size_t)(b * 64 + c * 16 + l15) * TT + k0 + kst * 32 + quad * 8);
            const bool diag = (u == nkb - 1);
            // exp2 in place for BOTH mt (sacc := P)
            #pragma unroll
            for (int mt = 0; mt < 2; mt++)
                #pragma unroll
                for (int c = 0; c < 4; c++)
                    #pragma unroll
                    for (int rr = 0; rr < 4; rr++){
                        float sv = sacc[mt][c][rr];
                        if (diag){
                            const int kg = k0 + c * 16 + l15;
                            const int qg = q0 + mt * 16 + quad * 4 + rr;
                            sv = (kg <= qg) ? sv : -1e30f;
                        }
                        sacc[mt][c][rr] = exp2f(sv);
                    }
            // mt0: P -> LDS (trunc), PV(mt0)
            #pragma unroll
            for (int c = 0; c < 4; c++)
                #pragma unroll
                for (int rr = 0; rr < 4; rr++)
                    sbuf[w][(quad * 4 + rr) * 72 + c * 16 + l15] =
                        (unsigned short)(__float_as_uint(sacc[0][c][rr]) >> 16);
            {
                const short8 pf0 = *(const short8*)&sbuf[w][l15 * 72 + quad * 8];
                const short8 pf1 = *(const short8*)&sbuf[w][l15 * 72 + 32 + quad * 8];
                Lk[0] = MFMA16(pf0, VONES, Lk[0]);
                Lk[0] = MFMA16(pf1, VONES, Lk[0]);
                #pragma unroll
                for (int c2 = 0; c2 < 4; c2++){
                    O[0][c2] = MFMA16(pf0, vf[c2][0], O[0][c2]);
                    O[0][c2] = MFMA16(pf1, vf[c2][1], O[0][c2]);
                }
            }
            // mt1: P -> LDS (same region; same-wave WAR ordered by lgkmcnt)
            #pragma unroll
            for (int c = 0; c < 4; c++)
                #pragma unroll
                for (int rr = 0; rr < 4; rr++)
                    sbuf[w][(quad * 4 + rr) * 72 + c * 16 + l15] =
                        (unsigned short)(__float_as_uint(sacc[1][c][rr]) >> 16);
            // QK(u+8) into sacc (P fully consumed), then prefetch kf(u+16).
            // Covers PV(mt1)'s LDS round-trip.
            if (u + 8 < nkb){
                qk8(qf, kf, sacc);
                if (u + 16 < nkb){
                    const int kn0 = (u + 16) * 64;
                    #pragma unroll
                    for (int c = 0; c < 4; c++)
                        #pragma unroll
                        for (int kst = 0; kst < 2; kst++)
                            kf[c][kst] = *(const short8*)(K + (size_t)(brow + kn0 + c * 16 + l15) * HH + kst * 32 + quad * 8);
                }
            }
            // PV(mt1)
            {
                const short8 pf0 = *(const short8*)&sbuf[w][l15 * 72 + quad * 8];
                const short8 pf1 = *(const short8*)&sbuf[w][l15 * 72 + 32 + quad * 8];
                Lk[1] = MFMA16(pf0, VONES, Lk[1]);
                Lk[1] = MFMA16(pf1, VONES, Lk[1]);
                #pragma unroll
                for (int c2 = 0; c2 < 4; c2++){
                    O[1][c2] = MFMA16(pf0, vf[c2][0], O[1][c2]);
                    O[1][c2] = MFMA16(pf1, vf[c2][1], O[1][c2]);
                }
            }
        }
    }
    // epilogue: two 16-row phases (mt = 0, 1). Idle waves contribute zeros.
    #pragma unroll 1
    for (int mt = 0; mt < 2; mt++){
        #pragma unroll
        for (int rr = 0; rr < 4; rr++){
            const int row = quad * 4 + rr;
            #pragma unroll
            for (int c2 = 0; c2 < 4; c2++)
                sbuf[w][row * 72 + c2 * 16 + l15] = f2bf(O[mt][c2][rr]);
            if (l15 == 0) lpart[w][row] = Lk[mt][rr];
        }
        __syncthreads();
        // reduce 16 rows x 64 h = 1024 over 512 threads
        #pragma unroll
        for (int i = 0; i < 2; i++){
            const int e = i * 512 + tid;
            const int r = e >> 6, h = e & 63;
            float num = 0.f, den = 0.f;
            #pragma unroll
            for (int ww = 0; ww < 8; ww++){
                num += bflo(sbuf[ww][r * 72 + h]);
                den += lpart[ww][r];
            }
            const float ov = num / den;
            const size_t gi = (size_t)(brow + q0 + mt * 16 + r) * HH + h;
            if (mode) ((float*)out)[gi] = ov;
            else      ((unsigned short*)out)[gi] = f2bf(ov);
        }
        __syncthreads();   // protect sbuf/lpart reuse by next phase
    }
}

extern "C" void kernel_launch(void* const* d_in, const int* in_sizes, int n_in,
                              void* d_out, int out_size, void* d_ws, size_t ws_size,
                              hipStream_t stream) {
    const void* x  = d_in[0];
    const void* Wq = d_in[1];
    const void* bq = d_in[2];
    const void* Wk = d_in[3];
    const void* bk = d_in[4];
    const void* Wv = d_in[5];
    const void* bv = d_in[6];

    unsigned short* Qw  = (unsigned short*)d_ws;            // 2 MB (pre-scaled)
    unsigned short* Kw  = Qw + (size_t)BT * HH;             // 2 MB
    unsigned short* VTw = Kw + (size_t)BT * HH;             // 2 MB  [b][h][t]
    unsigned short* wt  = VTw + (size_t)BT * HH;            // 288 KB
    int* flag  = (int*)(wt + (size_t)192 * EE);

    wt_kernel<<<36, 256, 0, stream>>>((const unsigned short*)x, Wq, Wk, Wv, wt, flag);
    qkv_kernel<<<1024, 256, 0, stream>>>(x, wt, bq, bk, bv, Qw, Kw, VTw, flag);
    attn_kernel<<<512, 512, 0, stream>>>(Qw, Kw, VTw, d_out, flag);
}

// Round 11
// 151.338 us; speedup vs baseline: 1.0742x; 1.0742x over previous
//
#include <hip/hip_runtime.h>

// Head: B=4 T=4096 E=768 H=64, causal attention, single head.
// Round 17: R16 with the rule-#20 scratch bug fixed. R16's epilogue used
// `#pragma unroll 1 for mt` -> runtime mt index into O[mt]/Lk[mt] -> compiler
// placed the ACCUMULATORS in scratch for the whole kernel (WRITE_SIZE 4->53MB,
// VGPR_Count unchanged at 100 — scratch isn't VGPR). Fix: fully unroll the
// epilogue (compile-time mt). Everything else identical to R16:
//  - P staged one mt-tile at a time -> LDS 18944B (was 37888) -> tests the
//    1-block/CU model (64KB pool): if right, 2 blocks/CU co-schedule.
//  - qkv/wt HELD at R14. lsum via ones-MFMA (R15). Trunc P-store (R13).
// Ledger: (512,2) bound mandatory (cap=256/arg2). Heavy-first z->qt.
// NEVER runtime-index register arrays (O/Lk/sacc) — scratch spill.
// Softmax without max-subtraction (logits bounded), Q pre-scaled 0.125*log2e.

#define BB 4
#define TT 4096
#define EE 768
#define HH 64
#define BT (BB*TT)

typedef __attribute__((ext_vector_type(8))) short short8;
typedef __attribute__((ext_vector_type(4))) float f32x4;
#define MFMA16(a,b,c) __builtin_amdgcn_mfma_f32_16x16x32_bf16(a,b,c,0,0,0)
#define QSCALE 0.18033688011112042f   // 0.125 * log2(e)

static __device__ __forceinline__ float bflo(unsigned a){ return __uint_as_float(a << 16); }
static __device__ __forceinline__ unsigned short f2bf(float f){
    unsigned x = __float_as_uint(f);
    x += 0x7fffu + ((x >> 16) & 1u);   // RNE
    return (unsigned short)(x >> 16);
}
template<int FP32>
static __device__ __forceinline__ float ldin(const void* p, int idx){
    if (FP32) return ((const float*)p)[idx];
    return bflo(((const unsigned short*)p)[idx]);
}

// ---------------- W transpose + fused dtype probe ----------------
template<int FP32>
static __device__ void wt_body(const void* W, int wi, int e0, unsigned short* wt){
    __shared__ unsigned short ts[64 * 72];
    const int tid = threadIdx.x;
    #pragma unroll
    for (int p = 0; p < 2; p++){
        int i = p * 256 + tid;
        int r = i >> 3, g = i & 7;
        unsigned short v[8];
        if (FP32){
            const float* src = (const float*)W + (size_t)(e0 + r) * HH + g * 8;
            const float4 a = *(const float4*)src, b = *(const float4*)(src + 4);
            v[0]=f2bf(a.x); v[1]=f2bf(a.y); v[2]=f2bf(a.z); v[3]=f2bf(a.w);
            v[4]=f2bf(b.x); v[5]=f2bf(b.y); v[6]=f2bf(b.z); v[7]=f2bf(b.w);
        } else {
            const unsigned short* src = (const unsigned short*)W + (size_t)(e0 + r) * HH + g * 8;
            #pragma unroll
            for (int j = 0; j < 8; j++) v[j] = src[j];
        }
        #pragma unroll
        for (int j = 0; j < 8; j++) ts[r * 72 + g * 8 + j] = v[j];
    }
    __syncthreads();
    #pragma unroll
    for (int p = 0; p < 2; p++){
        int i = p * 256 + tid;
        int h = i >> 3, g = i & 7;
        unsigned short v[8];
        #pragma unroll
        for (int j = 0; j < 8; j++) v[j] = ts[(g * 8 + j) * 72 + h];
        unsigned short* dst = wt + (size_t)(wi * 64 + h) * EE + e0 + g * 8;
        uint4 pk;
        pk.x = (unsigned)v[0] | ((unsigned)v[1] << 16);
        pk.y = (unsigned)v[2] | ((unsigned)v[3] << 16);
        pk.z = (unsigned)v[4] | ((unsigned)v[5] << 16);
        pk.w = (unsigned)v[6] | ((unsigned)v[7] << 16);
        *(uint4*)dst = pk;
    }
}
__global__ __launch_bounds__(256) void wt_kernel(
    const unsigned short* xu, const void* Wq, const void* Wk, const void* Wv,
    unsigned short* wt, int* flag){
    __shared__ int cnt;
    const int tid = threadIdx.x;
    if (tid == 0) cnt = 0;
    __syncthreads();
    int c = 0;
    #pragma unroll
    for (int i = 0; i < 16; i++){
        unsigned u = xu[tid * 16 + i];
        unsigned e = (u >> 7) & 0xFFu;
        if (e >= 140u) c++;              // |v| >= 2^13 decoded as bf16
    }
    atomicAdd(&cnt, c);
    __syncthreads();
    const int fp32 = (cnt > 32) ? 1 : 0;
    if (blockIdx.x == 0 && tid == 0) *flag = fp32;
    const int wi = blockIdx.x / 12;
    const int e0 = (blockIdx.x % 12) * 64;
    const void* W = (wi == 0) ? Wq : (wi == 1) ? Wk : Wv;
    if (fp32) wt_body<1>(W, wi, e0, wt);
    else      wt_body<0>(W, wi, e0, wt);
}

// ---------------- QKV: LDS-staged MFMA GEMM, pipelined staging (R14) ----------------
// grid 1024 = (512 m-tiles of 32 rows) x (2 n-halves of 96 cols), block 256.
// c+1's x/W global loads issued into regs during c's MFMA window.
template<int FP32>
static __device__ void qkv_body(const void* x, const unsigned short* wt,
    const void* bq, const void* bk, const void* bv,
    unsigned short* Qw, unsigned short* Kw, unsigned short* VTw,
    unsigned short* xs, unsigned short* wsl)
{
    const int tid = threadIdx.x, lane = tid & 63, w = tid >> 6;
    const int l15 = lane & 15, quad = lane >> 4;
    const int z = blockIdx.x;
    const int m0 = (z >> 1) * 32;
    const int nh = z & 1;               // n-half: frags nh*6 .. nh*6+5
    const int rh = (w & 1) * 16;
    const int ngl = (w >> 1) * 3;

    f32x4 acc[3];
    #pragma unroll
    for (int i = 0; i < 3; i++) acc[i] = (f32x4)(0.f);

    const int srow = tid >> 3, sg = tid & 7;

    // per-thread fixed source pointers (c advances by +64 elements)
    const float*          xsF = (const float*)x + (size_t)(m0 + srow) * EE + sg * 8;
    const unsigned short* xsB = (const unsigned short*)x + (size_t)(m0 + srow) * EE + sg * 8;
    const unsigned short* ws0 = wt + (size_t)(nh * 96 + srow) * EE + sg * 8;   // p=0: n=srow
    const unsigned short* ws1 = ws0 + (size_t)32 * EE;                          // p=1: n=32+srow
    const unsigned short* ws2 = ws0 + (size_t)64 * EE;                          // p=2: n=64+srow

    float4 xa, xb;      // FP32 prefetch regs
    short8 xv;          // bf16 prefetch reg
    short8 wr0, wr1, wr2;

    // prologue: issue c=0 loads
    if (FP32){ xa = *(const float4*)xsF; xb = *(const float4*)(xsF + 4); }
    else     { xv = *(const short8*)xsB; }
    wr0 = *(const short8*)ws0;
    wr1 = *(const short8*)ws1;
    wr2 = *(const short8*)ws2;

    for (int c = 0; c < 12; c++){
        __syncthreads();
        // stage x from regs
        {
            short8 v;
            if (FP32){
                v[0]=(short)f2bf(xa.x); v[1]=(short)f2bf(xa.y); v[2]=(short)f2bf(xa.z); v[3]=(short)f2bf(xa.w);
                v[4]=(short)f2bf(xb.x); v[5]=(short)f2bf(xb.y); v[6]=(short)f2bf(xb.z); v[7]=(short)f2bf(xb.w);
            } else {
                v = xv;
            }
            *(short8*)&xs[srow * 72 + sg * 8] = v;
        }
        // stage W from regs (same layout as before: n = p*32+srow, g2 = sg)
        *(short8*)&wsl[(     srow) * 72 + sg * 8] = wr0;
        *(short8*)&wsl[(32 + srow) * 72 + sg * 8] = wr1;
        *(short8*)&wsl[(64 + srow) * 72 + sg * 8] = wr2;
        // issue c+1 loads (WAR-safe: ds_writes above consumed regs at issue);
        // they complete during the MFMA phase below.
        if (c < 11){
            const int c1 = (c + 1) * 64;
            if (FP32){ xa = *(const float4*)(xsF + c1); xb = *(const float4*)(xsF + c1 + 4); }
            else     { xv = *(const short8*)(xsB + c1); }
            wr0 = *(const short8*)(ws0 + c1);
            wr1 = *(const short8*)(ws1 + c1);
            wr2 = *(const short8*)(ws2 + c1);
        }
        __syncthreads();
        #pragma unroll
        for (int kst = 0; kst < 2; kst++){
            const short8 a = *(const short8*)&xs[(rh + l15) * 72 + kst * 32 + quad * 8];
            #pragma unroll
            for (int nf = 0; nf < 3; nf++){
                const short8 bfr = *(const short8*)&wsl[((ngl + nf) * 16 + l15) * 72 + kst * 32 + quad * 8];
                acc[nf] = MFMA16(a, bfr, acc[nf]);
            }
        }
    }
    #pragma unroll
    for (int nf = 0; nf < 3; nf++){
        const int gi = nh * 6 + ngl + nf;   // global frag 0..11
        const int wi = gi >> 2;             // 0=Q 1=K 2=V
        const int h = (gi & 3) * 16 + l15;
        const void* bp = (wi == 0) ? bq : (wi == 1) ? bk : bv;
        const float bias = ldin<FP32>(bp, h);
        if (wi == 0){
            #pragma unroll
            for (int rr = 0; rr < 4; rr++){
                const int tok = m0 + rh + quad * 4 + rr;
                Qw[(size_t)tok * HH + h] = f2bf((acc[nf][rr] + bias) * QSCALE);
            }
        } else if (wi == 1){
            #pragma unroll
            for (int rr = 0; rr < 4; rr++){
                const int tok = m0 + rh + quad * 4 + rr;
                Kw[(size_t)tok * HH + h] = f2bf(acc[nf][rr] + bias);
            }
        } else {
            const int tok0 = m0 + rh + quad * 4;
            const int bloc = tok0 >> 12;
            const int tl = tok0 & 4095;
            uint2 pk;
            pk.x = (unsigned)f2bf(acc[nf][0] + bias) | ((unsigned)f2bf(acc[nf][1] + bias) << 16);
            pk.y = (unsigned)f2bf(acc[nf][2] + bias) | ((unsigned)f2bf(acc[nf][3] + bias) << 16);
            *(uint2*)&VTw[(size_t)(bloc * 64 + h) * TT + tl] = pk;
        }
    }
}
__global__ __launch_bounds__(256, 2) void qkv_kernel(
    const void* x, const unsigned short* wt,
    const void* bq, const void* bk, const void* bv,
    unsigned short* Qw, unsigned short* Kw, unsigned short* VTw, const int* flag){
    __shared__ unsigned short xs[32 * 72];    // 4.6 KB
    __shared__ unsigned short wsl[96 * 72];   // 13.8 KB
    if (*flag) qkv_body<1>(x, wt, bq, bk, bv, Qw, Kw, VTw, xs, wsl);
    else       qkv_body<0>(x, wt, bq, bk, bv, Qw, Kw, VTw, xs, wsl);
}

// ---------------- attn: small-LDS pipelined heavy-first split-K flash ----------------
static __device__ __forceinline__ void qk8(
    const short8 (&qf)[2][2], const short8 (&kf)[4][2], f32x4 (&s)[2][4])
{
    #pragma unroll
    for (int mt = 0; mt < 2; mt++)
        #pragma unroll
        for (int c = 0; c < 4; c++){
            s[mt][c] = (f32x4)(0.f);
            s[mt][c] = MFMA16(qf[mt][0], kf[c][0], s[mt][c]);
            s[mt][c] = MFMA16(qf[mt][1], kf[c][1], s[mt][c]);
        }
}
// grid 512 = (128 qt, heavy first) x (4 b), block 512 = 8 waves = 8 cyclic
// splits. P staged ONE mt-tile at a time -> LDS 18944 B -> 2 blocks/CU.
// __launch_bounds__(512,2): VGPR cap 128 — do not raise arg2.
__global__ __launch_bounds__(512, 2) void attn_kernel(
    const unsigned short* __restrict__ Q,
    const unsigned short* __restrict__ K, const unsigned short* __restrict__ VT,
    void* __restrict__ out, const int* __restrict__ flag)
{
    __shared__ unsigned short sbuf[8][1152];  // per-wave: P[16][72] / Opart[16][72]
    __shared__ float lpart[8][16];

    const int mode = *flag;
    const int z = blockIdx.x;
    const int b = z & 3;
    const int qt = 127 - (z >> 2);        // heavy tiles dispatched first
    const int q0 = qt * 32;
    const int nkb = (qt >> 1) + 1;        // key units; only the last needs masking
    const int tid = threadIdx.x;
    const int lane = tid & 63;
    const int w = tid >> 6;               // wave = split
    const int l15 = lane & 15, quad = lane >> 4;
    const int brow = b * TT;

    const short8 VONES = (short8)(short)0x3F80;  // bf16 1.0 splat (ones B-frag)

    f32x4 O[2][4];
    f32x4 Lk[2];                          // P row-sums via ones-MFMA
    #pragma unroll
    for (int mt = 0; mt < 2; mt++){
        Lk[mt] = (f32x4)(0.f);
        #pragma unroll
        for (int i = 0; i < 4; i++) O[mt][i] = (f32x4)(0.f);
    }

    if (w < nkb){
        // Q A-frags (pre-scaled by QSCALE)
        short8 qf[2][2];
        #pragma unroll
        for (int mt = 0; mt < 2; mt++)
            #pragma unroll
            for (int kst = 0; kst < 2; kst++)
                qf[mt][kst] = *(const short8*)(Q + (size_t)(brow + q0 + mt * 16 + l15) * HH + kst * 32 + quad * 8);

        // K frags for unit w + prologue QK
        short8 kf[4][2];
        #pragma unroll
        for (int c = 0; c < 4; c++)
            #pragma unroll
            for (int kst = 0; kst < 2; kst++)
                kf[c][kst] = *(const short8*)(K + (size_t)(brow + w * 64 + c * 16 + l15) * HH + kst * 32 + quad * 8);

        f32x4 sacc[2][4];
        qk8(qf, kf, sacc);
        if (w + 8 < nkb){
            const int kn0 = (w + 8) * 64;
            #pragma unroll
            for (int c = 0; c < 4; c++)
                #pragma unroll
                for (int kst = 0; kst < 2; kst++)
                    kf[c][kst] = *(const short8*)(K + (size_t)(brow + kn0 + c * 16 + l15) * HH + kst * 32 + quad * 8);
        }

        for (int u = w; u < nkb; u += 8){
            const int k0 = u * 64;
            // V^T frags (issued early, consumed at PV)
            short8 vf[4][2];
            #pragma unroll
            for (int c = 0; c < 4; c++)
                #pragma unroll
                for (int kst = 0; kst < 2; kst++)
                    vf[c][kst] = *(const short8*)(VT + (size_t)(b * 64 + c * 16 + l15) * TT + k0 + kst * 32 + quad * 8);
            const bool diag = (u == nkb - 1);
            // exp2 in place for BOTH mt (sacc := P)
            #pragma unroll
            for (int mt = 0; mt < 2; mt++)
                #pragma unroll
                for (int c = 0; c < 4; c++)
                    #pragma unroll
                    for (int rr = 0; rr < 4; rr++){
                        float sv = sacc[mt][c][rr];
                        if (diag){
                            const int kg = k0 + c * 16 + l15;
                            const int qg = q0 + mt * 16 + quad * 4 + rr;
                            sv = (kg <= qg) ? sv : -1e30f;
                        }
                        sacc[mt][c][rr] = exp2f(sv);
                    }
            // mt0: P -> LDS (trunc), PV(mt0)
            #pragma unroll
            for (int c = 0; c < 4; c++)
                #pragma unroll
                for (int rr = 0; rr < 4; rr++)
                    sbuf[w][(quad * 4 + rr) * 72 + c * 16 + l15] =
                        (unsigned short)(__float_as_uint(sacc[0][c][rr]) >> 16);
            {
                const short8 pf0 = *(const short8*)&sbuf[w][l15 * 72 + quad * 8];
                const short8 pf1 = *(const short8*)&sbuf[w][l15 * 72 + 32 + quad * 8];
                Lk[0] = MFMA16(pf0, VONES, Lk[0]);
                Lk[0] = MFMA16(pf1, VONES, Lk[0]);
                #pragma unroll
                for (int c2 = 0; c2 < 4; c2++){
                    O[0][c2] = MFMA16(pf0, vf[c2][0], O[0][c2]);
                    O[0][c2] = MFMA16(pf1, vf[c2][1], O[0][c2]);
                }
            }
            // mt1: P -> LDS (same region; same-wave WAR ordered by lgkmcnt)
            #pragma unroll
            for (int c = 0; c < 4; c++)
                #pragma unroll
                for (int rr = 0; rr < 4; rr++)
                    sbuf[w][(quad * 4 + rr) * 72 + c * 16 + l15] =
                        (unsigned short)(__float_as_uint(sacc[1][c][rr]) >> 16);
            // QK(u+8) into sacc (P fully consumed), then prefetch kf(u+16).
            // Covers PV(mt1)'s LDS round-trip.
            if (u + 8 < nkb){
                qk8(qf, kf, sacc);
                if (u + 16 < nkb){
                    const int kn0 = (u + 16) * 64;
                    #pragma unroll
                    for (int c = 0; c < 4; c++)
                        #pragma unroll
                        for (int kst = 0; kst < 2; kst++)
                            kf[c][kst] = *(const short8*)(K + (size_t)(brow + kn0 + c * 16 + l15) * HH + kst * 32 + quad * 8);
                }
            }
            // PV(mt1)
            {
                const short8 pf0 = *(const short8*)&sbuf[w][l15 * 72 + quad * 8];
                const short8 pf1 = *(const short8*)&sbuf[w][l15 * 72 + 32 + quad * 8];
                Lk[1] = MFMA16(pf0, VONES, Lk[1]);
                Lk[1] = MFMA16(pf1, VONES, Lk[1]);
                #pragma unroll
                for (int c2 = 0; c2 < 4; c2++){
                    O[1][c2] = MFMA16(pf0, vf[c2][0], O[1][c2]);
                    O[1][c2] = MFMA16(pf1, vf[c2][1], O[1][c2]);
                }
            }
        }
    }
    // epilogue: two 16-row phases, FULLY UNROLLED (compile-time mt — rule #20:
    // runtime mt would force O/Lk into scratch for the whole kernel).
    #pragma unroll
    for (int mt = 0; mt < 2; mt++){
        #pragma unroll
        for (int rr = 0; rr < 4; rr++){
            const int row = quad * 4 + rr;
            #pragma unroll
            for (int c2 = 0; c2 < 4; c2++)
                sbuf[w][row * 72 + c2 * 16 + l15] = f2bf(O[mt][c2][rr]);
            if (l15 == 0) lpart[w][row] = Lk[mt][rr];
        }
        __syncthreads();
        // reduce 16 rows x 64 h = 1024 over 512 threads
        #pragma unroll
        for (int i = 0; i < 2; i++){
            const int e = i * 512 + tid;
            const int r = e >> 6, h = e & 63;
            float num = 0.f, den = 0.f;
            #pragma unroll
            for (int ww = 0; ww < 8; ww++){
                num += bflo(sbuf[ww][r * 72 + h]);
                den += lpart[ww][r];
            }
            const float ov = num / den;
            const size_t gi = (size_t)(brow + q0 + mt * 16 + r) * HH + h;
            if (mode) ((float*)out)[gi] = ov;
            else      ((unsigned short*)out)[gi] = f2bf(ov);
        }
        __syncthreads();   // protect sbuf/lpart reuse by next phase
    }
}

extern "C" void kernel_launch(void* const* d_in, const int* in_sizes, int n_in,
                              void* d_out, int out_size, void* d_ws, size_t ws_size,
                              hipStream_t stream) {
    const void* x  = d_in[0];
    const void* Wq = d_in[1];
    const void* bq = d_in[2];
    const void* Wk = d_in[3];
    const void* bk = d_in[4];
    const void* Wv = d_in[5];
    const void* bv = d_in[6];

    unsigned short* Qw  = (unsigned short*)d_ws;            // 2 MB (pre-scaled)
    unsigned short* Kw  = Qw + (size_t)BT * HH;             // 2 MB
    unsigned short* VTw = Kw + (size_t)BT * HH;             // 2 MB  [b][h][t]
    unsigned short* wt  = VTw + (size_t)BT * HH;            // 288 KB
    int* flag  = (int*)(wt + (size_t)192 * EE);

    wt_kernel<<<36, 256, 0, stream>>>((const unsigned short*)x, Wq, Wk, Wv, wt, flag);
    qkv_kernel<<<1024, 256, 0, stream>>>(x, wt, bq, bk, bv, Qw, Kw, VTw, flag);
    attn_kernel<<<512, 512, 0, stream>>>(Qw, Kw, VTw, d_out, flag);
}

// Round 12
// 143.395 us; speedup vs baseline: 1.1337x; 1.0554x over previous
//
#include <hip/hip_runtime.h>

// Head: B=4 T=4096 E=768 H=64, causal attention, single head.
// Round 18: attn REVERTED to R15 verbatim (42.8us best; R16/R17 experiments
// falsified the LDS-residency theory — pool is 160KB, waves VGPR-capped at
// 16/CU; attn is issue-bound: ~130cyc MFMA + ~256cyc exp2 + ~150cyc VALU per
// key-unit, exp-per-logit irreducible). qkv: single-x-read merged tile —
// grid 512 x 512thr (8 waves = 2 row x 4 col groups), all 192 cols per
// m-tile, x staged ONCE (was twice -> 100MB). Fixes R7's occupancy mistake
// (same 16 waves/CU as R14). Keeps R14 reg-pipelined staging.
// Ledger: attn (512,2) bound mandatory (cap=256/arg2). Heavy-first z->qt.
// lsum via ones-MFMA. Trunc P-store. NEVER runtime-index register arrays.
// Softmax without max-subtraction (logits bounded), Q pre-scaled 0.125*log2e.

#define BB 4
#define TT 4096
#define EE 768
#define HH 64
#define BT (BB*TT)

typedef __attribute__((ext_vector_type(8))) short short8;
typedef __attribute__((ext_vector_type(4))) float f32x4;
#define MFMA16(a,b,c) __builtin_amdgcn_mfma_f32_16x16x32_bf16(a,b,c,0,0,0)
#define QSCALE 0.18033688011112042f   // 0.125 * log2(e)

static __device__ __forceinline__ float bflo(unsigned a){ return __uint_as_float(a << 16); }
static __device__ __forceinline__ unsigned short f2bf(float f){
    unsigned x = __float_as_uint(f);
    x += 0x7fffu + ((x >> 16) & 1u);   // RNE
    return (unsigned short)(x >> 16);
}
template<int FP32>
static __device__ __forceinline__ float ldin(const void* p, int idx){
    if (FP32) return ((const float*)p)[idx];
    return bflo(((const unsigned short*)p)[idx]);
}

// ---------------- W transpose + fused dtype probe ----------------
template<int FP32>
static __device__ void wt_body(const void* W, int wi, int e0, unsigned short* wt){
    __shared__ unsigned short ts[64 * 72];
    const int tid = threadIdx.x;
    #pragma unroll
    for (int p = 0; p < 2; p++){
        int i = p * 256 + tid;
        int r = i >> 3, g = i & 7;
        unsigned short v[8];
        if (FP32){
            const float* src = (const float*)W + (size_t)(e0 + r) * HH + g * 8;
            const float4 a = *(const float4*)src, b = *(const float4*)(src + 4);
            v[0]=f2bf(a.x); v[1]=f2bf(a.y); v[2]=f2bf(a.z); v[3]=f2bf(a.w);
            v[4]=f2bf(b.x); v[5]=f2bf(b.y); v[6]=f2bf(b.z); v[7]=f2bf(b.w);
        } else {
            const unsigned short* src = (const unsigned short*)W + (size_t)(e0 + r) * HH + g * 8;
            #pragma unroll
            for (int j = 0; j < 8; j++) v[j] = src[j];
        }
        #pragma unroll
        for (int j = 0; j < 8; j++) ts[r * 72 + g * 8 + j] = v[j];
    }
    __syncthreads();
    #pragma unroll
    for (int p = 0; p < 2; p++){
        int i = p * 256 + tid;
        int h = i >> 3, g = i & 7;
        unsigned short v[8];
        #pragma unroll
        for (int j = 0; j < 8; j++) v[j] = ts[(g * 8 + j) * 72 + h];
        unsigned short* dst = wt + (size_t)(wi * 64 + h) * EE + e0 + g * 8;
        uint4 pk;
        pk.x = (unsigned)v[0] | ((unsigned)v[1] << 16);
        pk.y = (unsigned)v[2] | ((unsigned)v[3] << 16);
        pk.z = (unsigned)v[4] | ((unsigned)v[5] << 16);
        pk.w = (unsigned)v[6] | ((unsigned)v[7] << 16);
        *(uint4*)dst = pk;
    }
}
__global__ __launch_bounds__(256) void wt_kernel(
    const unsigned short* xu, const void* Wq, const void* Wk, const void* Wv,
    unsigned short* wt, int* flag){
    __shared__ int cnt;
    const int tid = threadIdx.x;
    if (tid == 0) cnt = 0;
    __syncthreads();
    int c = 0;
    #pragma unroll
    for (int i = 0; i < 16; i++){
        unsigned u = xu[tid * 16 + i];
        unsigned e = (u >> 7) & 0xFFu;
        if (e >= 140u) c++;              // |v| >= 2^13 decoded as bf16
    }
    atomicAdd(&cnt, c);
    __syncthreads();
    const int fp32 = (cnt > 32) ? 1 : 0;
    if (blockIdx.x == 0 && tid == 0) *flag = fp32;
    const int wi = blockIdx.x / 12;
    const int e0 = (blockIdx.x % 12) * 64;
    const void* W = (wi == 0) ? Wq : (wi == 1) ? Wk : Wv;
    if (fp32) wt_body<1>(W, wi, e0, wt);
    else      wt_body<0>(W, wi, e0, wt);
}

// ---------------- QKV: merged-tile MFMA GEMM, pipelined staging ----------------
// grid 512 m-tiles of 32 rows; block 512 = 8 waves = 2 row-groups x 4
// col-groups; ALL 192 cols per block -> x staged ONCE. R14-style reg
// pipeline: c+1's x/W global loads issued during c's MFMA window.
template<int FP32>
static __device__ void qkv_body(const void* x, const unsigned short* wt,
    const void* bq, const void* bk, const void* bv,
    unsigned short* Qw, unsigned short* Kw, unsigned short* VTw,
    unsigned short* xs, unsigned short* wsl)
{
    const int tid = threadIdx.x, lane = tid & 63, w = tid >> 6;
    const int l15 = lane & 15, quad = lane >> 4;
    const int m0 = blockIdx.x * 32;
    const int rh = (w & 1) * 16;
    const int ngl = (w >> 1) * 3;        // col-frags ngl..ngl+2 (0..11)

    f32x4 acc[3];
    #pragma unroll
    for (int i = 0; i < 3; i++) acc[i] = (f32x4)(0.f);

    // x staging: 32 rows x 64 cols over 512 threads -> 4 vals/thread
    const int xrow = tid >> 4, xg = tid & 15;
    // W staging: 192 rows x 64 cols over 512 threads x 3 passes -> 8 vals
    const int wrow = tid >> 3, wg = tid & 7;

    const float*          xsF = (const float*)x + (size_t)(m0 + xrow) * EE + xg * 4;
    const unsigned short* xsB = (const unsigned short*)x + (size_t)(m0 + xrow) * EE + xg * 4;
    const unsigned short* ws0 = wt + (size_t)(      wrow) * EE + wg * 8;
    const unsigned short* ws1 = wt + (size_t)( 64 + wrow) * EE + wg * 8;
    const unsigned short* ws2 = wt + (size_t)(128 + wrow) * EE + wg * 8;

    float4 xa;          // FP32 prefetch reg (4 vals)
    uint2  xv;          // bf16 prefetch reg (4 vals)
    short8 wr0, wr1, wr2;

    // prologue: issue c=0 loads
    if (FP32) xa = *(const float4*)xsF;
    else      xv = *(const uint2*)xsB;
    wr0 = *(const short8*)ws0;
    wr1 = *(const short8*)ws1;
    wr2 = *(const short8*)ws2;

    for (int c = 0; c < 12; c++){
        __syncthreads();
        // stage x from regs (4 u16 = uint2)
        {
            uint2 v;
            if (FP32){
                v.x = (unsigned)f2bf(xa.x) | ((unsigned)f2bf(xa.y) << 16);
                v.y = (unsigned)f2bf(xa.z) | ((unsigned)f2bf(xa.w) << 16);
            } else {
                v = xv;
            }
            *(uint2*)&xs[xrow * 72 + xg * 4] = v;
        }
        // stage W from regs (rows wrow, 64+wrow, 128+wrow)
        *(short8*)&wsl[(      wrow) * 72 + wg * 8] = wr0;
        *(short8*)&wsl[( 64 + wrow) * 72 + wg * 8] = wr1;
        *(short8*)&wsl[(128 + wrow) * 72 + wg * 8] = wr2;
        // issue c+1 loads (regs consumed by the ds_writes above at issue)
        if (c < 11){
            const int c1 = (c + 1) * 64;
            if (FP32) xa = *(const float4*)(xsF + c1);
            else      xv = *(const uint2*)(xsB + c1);
            wr0 = *(const short8*)(ws0 + c1);
            wr1 = *(const short8*)(ws1 + c1);
            wr2 = *(const short8*)(ws2 + c1);
        }
        __syncthreads();
        #pragma unroll
        for (int kst = 0; kst < 2; kst++){
            const short8 a = *(const short8*)&xs[(rh + l15) * 72 + kst * 32 + quad * 8];
            #pragma unroll
            for (int nf = 0; nf < 3; nf++){
                const short8 bfr = *(const short8*)&wsl[((ngl + nf) * 16 + l15) * 72 + kst * 32 + quad * 8];
                acc[nf] = MFMA16(a, bfr, acc[nf]);
            }
        }
    }
    #pragma unroll
    for (int nf = 0; nf < 3; nf++){
        const int gi = ngl + nf;            // global frag 0..11
        const int wi = gi >> 2;             // 0=Q 1=K 2=V
        const int h = (gi & 3) * 16 + l15;
        const void* bp = (wi == 0) ? bq : (wi == 1) ? bk : bv;
        const float bias = ldin<FP32>(bp, h);
        if (wi == 0){
            #pragma unroll
            for (int rr = 0; rr < 4; rr++){
                const int tok = m0 + rh + quad * 4 + rr;
                Qw[(size_t)tok * HH + h] = f2bf((acc[nf][rr] + bias) * QSCALE);
            }
        } else if (wi == 1){
            #pragma unroll
            for (int rr = 0; rr < 4; rr++){
                const int tok = m0 + rh + quad * 4 + rr;
                Kw[(size_t)tok * HH + h] = f2bf(acc[nf][rr] + bias);
            }
        } else {
            const int tok0 = m0 + rh + quad * 4;
            const int bloc = tok0 >> 12;
            const int tl = tok0 & 4095;
            uint2 pk;
            pk.x = (unsigned)f2bf(acc[nf][0] + bias) | ((unsigned)f2bf(acc[nf][1] + bias) << 16);
            pk.y = (unsigned)f2bf(acc[nf][2] + bias) | ((unsigned)f2bf(acc[nf][3] + bias) << 16);
            *(uint2*)&VTw[(size_t)(bloc * 64 + h) * TT + tl] = pk;
        }
    }
}
__global__ __launch_bounds__(512, 2) void qkv_kernel(
    const void* x, const unsigned short* wt,
    const void* bq, const void* bk, const void* bv,
    unsigned short* Qw, unsigned short* Kw, unsigned short* VTw, const int* flag){
    __shared__ unsigned short xs[32 * 72];     // 4.6 KB
    __shared__ unsigned short wsl[192 * 72];   // 27.6 KB
    if (*flag) qkv_body<1>(x, wt, bq, bk, bv, Qw, Kw, VTw, xs, wsl);
    else       qkv_body<0>(x, wt, bq, bk, bv, Qw, Kw, VTw, xs, wsl);
}

// ---------------- attn: R15 verbatim (best measured: 42.8us) ----------------
static __device__ __forceinline__ void qk8(
    const short8 (&qf)[2][2], const short8 (&kf)[4][2], f32x4 (&s)[2][4])
{
    #pragma unroll
    for (int mt = 0; mt < 2; mt++)
        #pragma unroll
        for (int c = 0; c < 4; c++){
            s[mt][c] = (f32x4)(0.f);
            s[mt][c] = MFMA16(qf[mt][0], kf[c][0], s[mt][c]);
            s[mt][c] = MFMA16(qf[mt][1], kf[c][1], s[mt][c]);
        }
}
// grid 512 = (128 qt, heavy first) x (4 b), block 512 = 8 waves = 8 cyclic
// splits. __launch_bounds__(512,2): VGPR cap 128 — do not raise arg2.
__global__ __launch_bounds__(512, 2) void attn_kernel(
    const unsigned short* __restrict__ Q,
    const unsigned short* __restrict__ K, const unsigned short* __restrict__ VT,
    void* __restrict__ out, const int* __restrict__ flag)
{
    __shared__ unsigned short sbuf[8][2304];  // per-wave: P[2mt][16][72] / Opart[32][72]
    __shared__ float lpart[8][32];

    const int mode = *flag;
    const int z = blockIdx.x;
    const int b = z & 3;
    const int qt = 127 - (z >> 2);        // heavy tiles dispatched first
    const int q0 = qt * 32;
    const int nkb = (qt >> 1) + 1;        // key units; only the last needs masking
    const int tid = threadIdx.x;
    const int lane = tid & 63;
    const int w = tid >> 6;               // wave = split
    const int l15 = lane & 15, quad = lane >> 4;
    const int brow = b * TT;

    const short8 VONES = (short8)(short)0x3F80;  // bf16 1.0 splat (ones B-frag)

    f32x4 O[2][4];
    f32x4 Lk[2];                          // P row-sums via ones-MFMA
    #pragma unroll
    for (int mt = 0; mt < 2; mt++){
        Lk[mt] = (f32x4)(0.f);
        #pragma unroll
        for (int i = 0; i < 4; i++) O[mt][i] = (f32x4)(0.f);
    }

    if (w < nkb){
        // Q A-frags (pre-scaled by QSCALE)
        short8 qf[2][2];
        #pragma unroll
        for (int mt = 0; mt < 2; mt++)
            #pragma unroll
            for (int kst = 0; kst < 2; kst++)
                qf[mt][kst] = *(const short8*)(Q + (size_t)(brow + q0 + mt * 16 + l15) * HH + kst * 32 + quad * 8);

        // K frags for unit w + prologue QK
        short8 kf[4][2];
        #pragma unroll
        for (int c = 0; c < 4; c++)
            #pragma unroll
            for (int kst = 0; kst < 2; kst++)
                kf[c][kst] = *(const short8*)(K + (size_t)(brow + w * 64 + c * 16 + l15) * HH + kst * 32 + quad * 8);

        f32x4 sacc[2][4];
        qk8(qf, kf, sacc);
        if (w + 8 < nkb){
            const int kn0 = (w + 8) * 64;
            #pragma unroll
            for (int c = 0; c < 4; c++)
                #pragma unroll
                for (int kst = 0; kst < 2; kst++)
                    kf[c][kst] = *(const short8*)(K + (size_t)(brow + kn0 + c * 16 + l15) * HH + kst * 32 + quad * 8);
        }

        for (int u = w; u < nkb; u += 8){
            const int k0 = u * 64;
            // V^T frags (issued early, consumed at PV)
            short8 vf[4][2];
            #pragma unroll
            for (int c = 0; c < 4; c++)
                #pragma unroll
                for (int kst = 0; kst < 2; kst++)
                    vf[c][kst] = *(const short8*)(VT + (size_t)(b * 64 + c * 16 + l15) * TT + k0 + kst * 32 + quad * 8);
            const bool diag = (u == nkb - 1);
            // softmax(u): sacc -> P in LDS (bf16 TRUNC store), no VALU lsum
            #pragma unroll
            for (int mt = 0; mt < 2; mt++){
                #pragma unroll
                for (int c = 0; c < 4; c++){
                    #pragma unroll
                    for (int rr = 0; rr < 4; rr++){
                        float sv = sacc[mt][c][rr];
                        if (diag){
                            const int kg = k0 + c * 16 + l15;
                            const int qg = q0 + mt * 16 + quad * 4 + rr;
                            sv = (kg <= qg) ? sv : -1e30f;
                        }
                        const float p = exp2f(sv);
                        sbuf[w][mt * 1152 + (quad * 4 + rr) * 72 + c * 16 + l15] =
                            (unsigned short)(__float_as_uint(p) >> 16);
                    }
                }
            }
            // QK(u+8) into sacc (kf holds u+8's K), then prefetch kf(u+16).
            // Issued between P-store and P-read: covers PV's LDS wait.
            if (u + 8 < nkb){
                qk8(qf, kf, sacc);
                if (u + 16 < nkb){
                    const int kn0 = (u + 16) * 64;
                    #pragma unroll
                    for (int c = 0; c < 4; c++)
                        #pragma unroll
                        for (int kst = 0; kst < 2; kst++)
                            kf[c][kst] = *(const short8*)(K + (size_t)(brow + kn0 + c * 16 + l15) * HH + kst * 32 + quad * 8);
                }
            }
            // O += P V ; Lk += P row-sums (ones B-frag)
            #pragma unroll
            for (int mt = 0; mt < 2; mt++){
                const short8 pf0 = *(const short8*)&sbuf[w][mt * 1152 + l15 * 72 + quad * 8];
                const short8 pf1 = *(const short8*)&sbuf[w][mt * 1152 + l15 * 72 + 32 + quad * 8];
                Lk[mt] = MFMA16(pf0, VONES, Lk[mt]);
                Lk[mt] = MFMA16(pf1, VONES, Lk[mt]);
                #pragma unroll
                for (int c2 = 0; c2 < 4; c2++){
                    O[mt][c2] = MFMA16(pf0, vf[c2][0], O[mt][c2]);
                    O[mt][c2] = MFMA16(pf1, vf[c2][1], O[mt][c2]);
                }
            }
        }
    }
    // epilogue: per-wave partials into sbuf (idle waves contribute zeros).
    // Lk C-layout: row = quad*4+rr, all 16 cols equal -> l15==0 lane writes.
    #pragma unroll
    for (int mt = 0; mt < 2; mt++)
        #pragma unroll
        for (int rr = 0; rr < 4; rr++){
            const int row = mt * 16 + quad * 4 + rr;
            #pragma unroll
            for (int c2 = 0; c2 < 4; c2++)
                sbuf[w][row * 72 + c2 * 16 + l15] = f2bf(O[mt][c2][rr]);
            if (l15 == 0) lpart[w][row] = Lk[mt][rr];
        }
    __syncthreads();
    // block reduction: 32 rows x 64 h = 2048 over 512 threads
    #pragma unroll
    for (int i = 0; i < 4; i++){
        const int e = i * 512 + tid;
        const int r = e >> 6, h = e & 63;
        float num = 0.f, den = 0.f;
        #pragma unroll
        for (int ww = 0; ww < 8; ww++){
            num += bflo(sbuf[ww][r * 72 + h]);
            den += lpart[ww][r];
        }
        const float ov = num / den;
        const size_t gi = (size_t)(brow + q0 + r) * HH + h;
        if (mode) ((float*)out)[gi] = ov;
        else      ((unsigned short*)out)[gi] = f2bf(ov);
    }
}

extern "C" void kernel_launch(void* const* d_in, const int* in_sizes, int n_in,
                              void* d_out, int out_size, void* d_ws, size_t ws_size,
                              hipStream_t stream) {
    const void* x  = d_in[0];
    const void* Wq = d_in[1];
    const void* bq = d_in[2];
    const void* Wk = d_in[3];
    const void* bk = d_in[4];
    const void* Wv = d_in[5];
    const void* bv = d_in[6];

    unsigned short* Qw  = (unsigned short*)d_ws;            // 2 MB (pre-scaled)
    unsigned short* Kw  = Qw + (size_t)BT * HH;             // 2 MB
    unsigned short* VTw = Kw + (size_t)BT * HH;             // 2 MB  [b][h][t]
    unsigned short* wt  = VTw + (size_t)BT * HH;            // 288 KB
    int* flag  = (int*)(wt + (size_t)192 * EE);

    wt_kernel<<<36, 256, 0, stream>>>((const unsigned short*)x, Wq, Wk, Wv, wt, flag);
    qkv_kernel<<<512, 512, 0, stream>>>(x, wt, bq, bk, bv, Qw, Kw, VTw, flag);
    attn_kernel<<<512, 512, 0, stream>>>(Qw, Kw, VTw, d_out, flag);
}